// Round 11
// baseline (145.652 us; speedup 1.0000x reference)
//
#include <hip/hip_runtime.h>
#include <hip/hip_bf16.h>
#include <cstdint>
#include <cstddef>

typedef short bf16x8 __attribute__((ext_vector_type(8)));
typedef float f32x4 __attribute__((ext_vector_type(4)));
typedef unsigned short u16x8 __attribute__((ext_vector_type(8)));

#define DEV __device__ __forceinline__

DEV void gload16(const void* g, void* l) {
  __builtin_amdgcn_global_load_lds((const __attribute__((address_space(1))) void*)g,
                                   (__attribute__((address_space(3))) void*)l,
                                   16, 0, 0);
}

DEV unsigned short f2bf(float f) {
  __hip_bfloat16 h = __float2bfloat16(f);
  return *reinterpret_cast<unsigned short*>(&h);
}

DEV float b2f(unsigned short u) {
  union { float f; unsigned int i; } v;
  v.i = ((unsigned int)u) << 16;
  return v.f;
}

// ---- prep: Wvt[d][k] = sum_h WqkvV ; Wst[m][d] = sum_h Wout. One kernel, role by bid ----
__global__ __launch_bounds__(256) void k_prep(const float* __restrict__ Wqkv,
                                              const float* __restrict__ Wout,
                                              unsigned short* __restrict__ Wvt,
                                              unsigned short* __restrict__ Wst) {
  const int bid = blockIdx.x, t = threadIdx.x;
  if (bid < 1024) {
    int gid = bid * 256 + t;  // 2048 k x 128 d
    int k = gid >> 7, d = gid & 127;
    const float* p = Wqkv + (size_t)k * 6144 + 256 + d;
    float s = 0.f;
#pragma unroll
    for (int h = 0; h < 16; ++h) s += __builtin_nontemporal_load(p + h * 384);
    Wvt[(size_t)d * 2048 + k] = f2bf(s);
  } else {
    int gid = (bid - 1024) * 256 + t;  // 128 d x 2048 m
    int d = gid >> 11, m = gid & 2047;
    const float* p = Wout + (size_t)d * 2048 + m;
    float s = 0.f;
#pragma unroll
    for (int h = 0; h < 16; ++h) s += __builtin_nontemporal_load(p + h * 262144);
    Wst[(size_t)m * 128 + d] = f2bf(s);
  }
}

// ---- beff[m] = bout[m] + sum_d (sum_h bqkv[h][256+d]) * Ws[d][m] ----
__global__ __launch_bounds__(256) void k_beff(const float* __restrict__ bqkv,
                                              const unsigned short* __restrict__ Wst,
                                              const float* __restrict__ bout,
                                              float* __restrict__ be) {
  __shared__ float bv[128];
  int t = threadIdx.x;
  if (t < 128) {
    float s = 0.f;
#pragma unroll
    for (int h = 0; h < 16; ++h) s += bqkv[h * 384 + 256 + t];
    bv[t] = s;
  }
  __syncthreads();
  int m = blockIdx.x * 256 + t;  // grid 8
  float s = bout[m];
  const unsigned short* wr = Wst + (size_t)m * 128;
  for (int d = 0; d < 128; ++d) s = fmaf(bv[d], b2f(wr[d]), s);
  be[m] = s;
}

// ---- GEMM1: T[16384][128] bf16 = X(fp32, cvt in-reg) * Wvt^T ----
// 1024 blocks x 256 thr (4 waves, n split 4-way: wave w owns cols w*32..w*32+31),
// m-tile 16, BK=64, B double-buffered LDS (gload16 + (row&7)<<4 swizzle both-sides),
// A = NT fp32 loads + in-reg cvt (all waves read same 16 rows -> L1 broadcast).
// launch_bounds(256,4): 4 blocks/CU (LDS 32 KB) -> 16 waves/CU for BW latency hiding.
__global__ __launch_bounds__(256, 4) void k_gemm1(const float* __restrict__ X,
                                                  const unsigned short* __restrict__ Wvt,
                                                  unsigned short* __restrict__ T) {
  __shared__ char bs[2][16384];
  const int t = threadIdx.x, lane = t & 63, w = t >> 6;
  const int l15 = lane & 15, l4 = lane >> 4;
  const int m0 = blockIdx.x * 16;

  int srow[4], scol[4];
#pragma unroll
  for (int c = 0; c < 4; ++c) {
    srow[c] = c * 32 + (t >> 3);
    scol[c] = ((t & 7) * 16) ^ ((srow[c] & 7) << 4);
  }
  const float* xrow = X + (size_t)(m0 + l15) * 2048;

  f32x4 acc[2];
#pragma unroll
  for (int ni = 0; ni < 2; ++ni)
#pragma unroll
    for (int r = 0; r < 4; ++r) acc[ni][r] = 0.f;

#define STAGE1(kt2, q)                                                         \
  _Pragma("unroll") for (int c = 0; c < 4; ++c)                                \
      gload16((const char*)Wvt + (size_t)srow[c] * 4096 + (kt2) * 128 + scol[c],\
              bs[q] + c * 4096 + w * 1024);
#define ALOAD(ra, kt2)                                                         \
  _Pragma("unroll") for (int i = 0; i < 4; ++i)                                \
      ra[i] = __builtin_nontemporal_load(                                      \
          (const f32x4*)(xrow + (kt2) * 64 + (i >> 1) * 32 + l4 * 8 + (i & 1) * 4));
#define COMP1(q, ra)                                                           \
  do {                                                                         \
    bf16x8 af[2];                                                              \
    _Pragma("unroll") for (int ks = 0; ks < 2; ++ks) {                         \
      u16x8 u;                                                                 \
      _Pragma("unroll") for (int jj = 0; jj < 4; ++jj) {                       \
        u[jj] = f2bf(ra[ks * 2][jj]); u[jj + 4] = f2bf(ra[ks * 2 + 1][jj]);    \
      }                                                                        \
      af[ks] = (bf16x8)u;                                                      \
    }                                                                          \
    _Pragma("unroll") for (int ni = 0; ni < 2; ++ni)                           \
    _Pragma("unroll") for (int ks = 0; ks < 2; ++ks) {                         \
      int row = w * 32 + ni * 16 + l15;                                        \
      int byt = (ks * 64 + l4 * 16) ^ ((row & 7) << 4);                        \
      bf16x8 bf = *(const bf16x8*)(bs[q] + row * 128 + byt);                   \
      acc[ni] = __builtin_amdgcn_mfma_f32_16x16x32_bf16(af[ks], bf, acc[ni], 0, 0, 0); \
    }                                                                          \
  } while (0)

  f32x4 raA[4], raB[4];
  STAGE1(0, 0) ALOAD(raA, 0)
  __syncthreads();
#pragma unroll 1
  for (int kt = 0; kt < 32; kt += 2) {
    STAGE1(kt + 1, 1) ALOAD(raB, kt + 1)
    COMP1(0, raA);
    __syncthreads();
    if (kt + 2 < 32) { STAGE1(kt + 2, 0) ALOAD(raA, kt + 2) }
    COMP1(1, raB);
    __syncthreads();
  }
#undef STAGE1
#undef ALOAD
#undef COMP1

#pragma unroll
  for (int ni = 0; ni < 2; ++ni)
#pragma unroll
    for (int r = 0; r < 4; ++r) {
      int row = m0 + l4 * 4 + r;
      int col = w * 32 + ni * 16 + l15;
      T[(size_t)row * 128 + col] = f2bf(acc[ni][r]);
    }
}

// ---- GEMM2: Y[16384][2048] fp32 = T * Wst^T + beff.  K=128 single sweep ----
// grid (256 m, 16 n) x 256 thr (4 waves x 16 rows). B-tile 32 KB one-shot stage ->
// launch_bounds(256,4): 4 blocks/CU. T-slices L2-hot across the 16 n-blocks.
__global__ __launch_bounds__(256, 4) void k_gemm2(const unsigned short* __restrict__ Tm,
                                                  const unsigned short* __restrict__ Wst,
                                                  const float* __restrict__ be,
                                                  float* __restrict__ Y) {
  __shared__ char bs[32768];
  const int t = threadIdx.x, lane = t & 63, w = t >> 6;
  const int l15 = lane & 15, l4 = lane >> 4;
  const int m0 = blockIdx.x * 64, n0 = blockIdx.y * 128;

#pragma unroll
  for (int c = 0; c < 8; ++c) {
    int row = c * 16 + (t >> 4);
    int sc = ((t & 15) * 16) ^ ((row & 7) << 4);
    gload16((const char*)Wst + (size_t)(n0 + row) * 256 + sc, bs + c * 4096 + w * 1024);
  }
  const unsigned short* trow = Tm + (size_t)(m0 + w * 16 + l15) * 128;
  bf16x8 afr[4];
#pragma unroll
  for (int kq = 0; kq < 4; ++kq) afr[kq] = *(const bf16x8*)(trow + kq * 32 + l4 * 8);
  __syncthreads();

  f32x4 acc[8];
#pragma unroll
  for (int nf = 0; nf < 8; ++nf)
#pragma unroll
    for (int r = 0; r < 4; ++r) acc[nf][r] = 0.f;

#pragma unroll
  for (int nf = 0; nf < 8; ++nf) {
    int row = nf * 16 + l15;
#pragma unroll
    for (int kq = 0; kq < 4; ++kq) {
      int byt = (kq * 64 + l4 * 16) ^ ((row & 7) << 4);
      bf16x8 bf = *(const bf16x8*)(bs + row * 256 + byt);
      acc[nf] = __builtin_amdgcn_mfma_f32_16x16x32_bf16(afr[kq], bf, acc[nf], 0, 0, 0);
    }
  }

#pragma unroll
  for (int nf = 0; nf < 8; ++nf) {
    int n = n0 + nf * 16 + l15;
    float bv = be[n];
#pragma unroll
    for (int r = 0; r < 4; ++r) {
      int row = m0 + w * 16 + l4 * 4 + r;
      Y[(size_t)row * 2048 + n] = acc[nf][r] + bv;
    }
  }
}

extern "C" void kernel_launch(void* const* d_in, const int* in_sizes, int n_in,
                              void* d_out, int out_size, void* d_ws, size_t ws_size,
                              hipStream_t stream) {
  const float* x    = (const float*)d_in[0];
  const float* Wqkv = (const float*)d_in[1];
  const float* bqkv = (const float*)d_in[2];
  const float* Wout = (const float*)d_in[3];
  const float* bout = (const float*)d_in[4];
  float* y = (float*)d_out;

  char* ws = (char*)d_ws;
  unsigned short* Wvt  = (unsigned short*)(ws);             //   524,288 B  [128][2048] bf16
  unsigned short* Wst  = (unsigned short*)(ws + 524288);    //   524,288 B  [2048][128] bf16
  float*          beff = (float*)(ws + 1048576);            //     8,192 B
  unsigned short* T    = (unsigned short*)(ws + 1056768);   // 4,194,304 B  [16384][128] bf16

  k_prep<<<2048, 256, 0, stream>>>(Wqkv, Wout, Wvt, Wst);
  k_beff<<<8, 256, 0, stream>>>(bqkv, Wst, bout, beff);
  k_gemm1<<<1024, 256, 0, stream>>>(x, Wvt, T);
  k_gemm2<<<dim3(256, 16), 256, 0, stream>>>(T, Wst, beff, y);
}

// Round 12
// 83.451 us; speedup vs baseline: 1.7454x; 1.7454x over previous
//
#include <hip/hip_runtime.h>
#include <hip/hip_bf16.h>
#include <cstdint>
#include <cstddef>

typedef short bf16x8 __attribute__((ext_vector_type(8)));
typedef float f32x4 __attribute__((ext_vector_type(4)));
typedef unsigned short u16x8 __attribute__((ext_vector_type(8)));

#define DEV __device__ __forceinline__

DEV void gload16(const void* g, void* l) {
  __builtin_amdgcn_global_load_lds((const __attribute__((address_space(1))) void*)g,
                                   (__attribute__((address_space(3))) void*)l,
                                   16, 0, 0);
}

DEV unsigned short f2bf(float f) {
  __hip_bfloat16 h = __float2bfloat16(f);
  return *reinterpret_cast<unsigned short*>(&h);
}

DEV float b2f(unsigned short u) {
  union { float f; unsigned int i; } v;
  v.i = ((unsigned int)u) << 16;
  return v.f;
}

// ---- prep: Wvt[d][k] = sum_h WqkvV ; Wst[m][d] = sum_h Wout. One kernel, role by bid ----
__global__ __launch_bounds__(256) void k_prep(const float* __restrict__ Wqkv,
                                              const float* __restrict__ Wout,
                                              unsigned short* __restrict__ Wvt,
                                              unsigned short* __restrict__ Wst) {
  const int bid = blockIdx.x, t = threadIdx.x;
  if (bid < 1024) {
    int gid = bid * 256 + t;  // 2048 k x 128 d
    int k = gid >> 7, d = gid & 127;
    const float* p = Wqkv + (size_t)k * 6144 + 256 + d;
    float s = 0.f;
#pragma unroll
    for (int h = 0; h < 16; ++h) s += __builtin_nontemporal_load(p + h * 384);
    Wvt[(size_t)d * 2048 + k] = f2bf(s);
  } else {
    int gid = (bid - 1024) * 256 + t;  // 128 d x 2048 m
    int d = gid >> 11, m = gid & 2047;
    const float* p = Wout + (size_t)d * 2048 + m;
    float s = 0.f;
#pragma unroll
    for (int h = 0; h < 16; ++h) s += __builtin_nontemporal_load(p + h * 262144);
    Wst[(size_t)m * 128 + d] = f2bf(s);
  }
}

// ---- beff[m] = bout[m] + sum_d (sum_h bqkv[h][256+d]) * Ws[d][m] ----
__global__ __launch_bounds__(256) void k_beff(const float* __restrict__ bqkv,
                                              const unsigned short* __restrict__ Wst,
                                              const float* __restrict__ bout,
                                              float* __restrict__ be) {
  __shared__ float bv[128];
  int t = threadIdx.x;
  if (t < 128) {
    float s = 0.f;
#pragma unroll
    for (int h = 0; h < 16; ++h) s += bqkv[h * 384 + 256 + t];
    bv[t] = s;
  }
  __syncthreads();
  int m = blockIdx.x * 256 + t;  // grid 8
  float s = bout[m];
  const unsigned short* wr = Wst + (size_t)m * 128;
  for (int d = 0; d < 128; ++d) s = fmaf(bv[d], b2f(wr[d]), s);
  be[m] = s;
}

// ---- GEMM1: T[16384][128] bf16 = X(fp32) * Wvt^T ----
// 512 blocks x 256 thr (4 waves: wm=w>>1 16-row half, wn=w&1 64-col half), m-tile 32, BK=64.
// r12 redesign (r11 was latency-bound: MfmaUtil 3%, HBM 0.8 TB/s):
//  (1) x staged via global_load_lds (coalesced fp32, 16B-granular XOR swizzle both-sides)
//      — kills r11's 16-row-stride fragmented register gather;
//  (2) TRIPLE-buffered counted-vmcnt pipeline (r8 machinery): stage t+2 while computing t,
//      vmcnt(12) = 6 loads x 2 tiles in flight; no vmcnt(0) drain in main loop.
// LDS 3 x (8KB x + 16KB Wvt) = 72KB -> 2 blocks/CU.
__global__ __launch_bounds__(256, 2) void k_gemm1(const float* __restrict__ X,
                                                  const unsigned short* __restrict__ Wvt,
                                                  unsigned short* __restrict__ T) {
  __shared__ char smem[73728];
  const int t = threadIdx.x, lane = t & 63, w = t >> 6;
  const int wm = w >> 1, wn = w & 1;
  const int l15 = lane & 15, l4 = lane >> 4;
  const int m0 = blockIdx.x * 32;

  // staging addresses (precomputed, pre-swizzled source per rule #21)
  int xrow_[2], xsrc_[2];
#pragma unroll
  for (int c = 0; c < 2; ++c) {
    xrow_[c] = c * 16 + w * 4 + (lane >> 4);
    xsrc_[c] = ((lane & 15) ^ (xrow_[c] & 7)) << 4;
  }
  int wrow_[4], wsrc_[4];
#pragma unroll
  for (int c = 0; c < 4; ++c) {
    wrow_[c] = c * 32 + w * 8 + (lane >> 3);
    wsrc_[c] = (((lane & 7) << 4)) ^ ((wrow_[c] & 7) << 4);
  }

  f32x4 acc[4];
#pragma unroll
  for (int ni = 0; ni < 4; ++ni)
#pragma unroll
    for (int r = 0; r < 4; ++r) acc[ni][r] = 0.f;

#define VMCNT(n) asm volatile("s_waitcnt vmcnt(" #n ")" ::: "memory")
#define BAR() __builtin_amdgcn_s_barrier()
#define SCHED0() __builtin_amdgcn_sched_barrier(0)

#define STAGE(tt, buf)                                                         \
  do {                                                                         \
    _Pragma("unroll") for (int c = 0; c < 2; ++c)                              \
        gload16((const char*)(X + (size_t)(m0 + xrow_[c]) * 2048) +            \
                    (tt) * 256 + xsrc_[c],                                     \
                smem + (buf) * 24576 + c * 4096 + w * 1024);                   \
    _Pragma("unroll") for (int c = 0; c < 4; ++c)                              \
        gload16((const char*)Wvt + (size_t)wrow_[c] * 4096 + (tt) * 128 +      \
                    wsrc_[c],                                                  \
                smem + (buf) * 24576 + 8192 + c * 4096 + w * 1024);            \
  } while (0)

#define COMPUTE(buf)                                                           \
  do {                                                                         \
    const char* xs = smem + (buf) * 24576;                                     \
    const char* ws = smem + (buf) * 24576 + 8192;                              \
    const int arow = wm * 16 + l15;                                            \
    const char* xr = xs + arow * 256;                                          \
    const int aswz = (arow & 7) << 4;                                          \
    bf16x8 af[2];                                                              \
    _Pragma("unroll") for (int ks = 0; ks < 2; ++ks) {                         \
      f32x4 a0 = *(const f32x4*)(xr + ((ks * 128 + l4 * 32) ^ aswz));          \
      f32x4 a1 = *(const f32x4*)(xr + ((ks * 128 + l4 * 32 + 16) ^ aswz));     \
      u16x8 u;                                                                 \
      _Pragma("unroll") for (int jj = 0; jj < 4; ++jj) {                       \
        u[jj] = f2bf(a0[jj]); u[jj + 4] = f2bf(a1[jj]);                        \
      }                                                                        \
      af[ks] = (bf16x8)u;                                                      \
    }                                                                          \
    _Pragma("unroll") for (int ni = 0; ni < 4; ++ni) {                         \
      const int brow = wn * 64 + ni * 16 + l15;                                \
      const int bswz = (brow & 7) << 4;                                        \
      _Pragma("unroll") for (int ks = 0; ks < 2; ++ks) {                       \
        bf16x8 bf = *(const bf16x8*)(ws + brow * 128 +                         \
                                     ((ks * 64 + l4 * 16) ^ bswz));            \
        acc[ni] = __builtin_amdgcn_mfma_f32_16x16x32_bf16(af[ks], bf,          \
                                                          acc[ni], 0, 0, 0);   \
      }                                                                        \
    }                                                                          \
  } while (0)

// main-loop tile: stage t+2, wait own tile resident (12 newer loads in flight), compute
#define TILE(tt, bR, bS)                                                       \
  STAGE((tt) + 2, bS); VMCNT(12); BAR(); SCHED0();                             \
  COMPUTE(bR); SCHED0(); BAR();

  // prologue: tiles 0,1 into bufs 0,1 (12 outstanding)
  STAGE(0, 0);
  STAGE(1, 1);

#pragma unroll 1
  for (int it = 0; it < 10; ++it) {
    const int tb = it * 3;
    TILE(tb + 0, 0, 2)
    TILE(tb + 1, 1, 0)
    TILE(tb + 2, 2, 1)
  }
  // peeled tail: tiles 30 (buf0), 31 (buf1); no more staging
  VMCNT(6);  BAR(); SCHED0(); COMPUTE(0); SCHED0(); BAR();
  VMCNT(0);  BAR(); SCHED0(); COMPUTE(1);

#undef TILE
#undef COMPUTE
#undef STAGE
#undef VMCNT
#undef BAR
#undef SCHED0

#pragma unroll
  for (int ni = 0; ni < 4; ++ni)
#pragma unroll
    for (int r = 0; r < 4; ++r) {
      int row = m0 + wm * 16 + l4 * 4 + r;
      int col = wn * 64 + ni * 16 + l15;
      T[(size_t)row * 128 + col] = f2bf(acc[ni][r]);
    }
}

// ---- GEMM2: Y[16384][2048] fp32 = T * Wst^T + beff.  K=128 single sweep ----
// grid (256 m, 16 n) x 256 thr (4 waves x 16 rows). B-tile 32 KB one-shot stage ->
// launch_bounds(256,4): 4 blocks/CU. T-slices L2-hot across the 16 n-blocks.
__global__ __launch_bounds__(256, 4) void k_gemm2(const unsigned short* __restrict__ Tm,
                                                  const unsigned short* __restrict__ Wst,
                                                  const float* __restrict__ be,
                                                  float* __restrict__ Y) {
  __shared__ char bs[32768];
  const int t = threadIdx.x, lane = t & 63, w = t >> 6;
  const int l15 = lane & 15, l4 = lane >> 4;
  const int m0 = blockIdx.x * 64, n0 = blockIdx.y * 128;

#pragma unroll
  for (int c = 0; c < 8; ++c) {
    int row = c * 16 + (t >> 4);
    int sc = ((t & 15) * 16) ^ ((row & 7) << 4);
    gload16((const char*)Wst + (size_t)(n0 + row) * 256 + sc, bs + c * 4096 + w * 1024);
  }
  const unsigned short* trow = Tm + (size_t)(m0 + w * 16 + l15) * 128;
  bf16x8 afr[4];
#pragma unroll
  for (int kq = 0; kq < 4; ++kq) afr[kq] = *(const bf16x8*)(trow + kq * 32 + l4 * 8);
  __syncthreads();

  f32x4 acc[8];
#pragma unroll
  for (int nf = 0; nf < 8; ++nf)
#pragma unroll
    for (int r = 0; r < 4; ++r) acc[nf][r] = 0.f;

#pragma unroll
  for (int nf = 0; nf < 8; ++nf) {
    int row = nf * 16 + l15;
#pragma unroll
    for (int kq = 0; kq < 4; ++kq) {
      int byt = (kq * 64 + l4 * 16) ^ ((row & 7) << 4);
      bf16x8 bf = *(const bf16x8*)(bs + row * 256 + byt);
      acc[nf] = __builtin_amdgcn_mfma_f32_16x16x32_bf16(afr[kq], bf, acc[nf], 0, 0, 0);
    }
  }

#pragma unroll
  for (int nf = 0; nf < 8; ++nf) {
    int n = n0 + nf * 16 + l15;
    float bv = be[n];
#pragma unroll
    for (int r = 0; r < 4; ++r) {
      int row = m0 + w * 16 + l4 * 4 + r;
      Y[(size_t)row * 2048 + n] = acc[nf][r] + bv;
    }
  }
}

extern "C" void kernel_launch(void* const* d_in, const int* in_sizes, int n_in,
                              void* d_out, int out_size, void* d_ws, size_t ws_size,
                              hipStream_t stream) {
  const float* x    = (const float*)d_in[0];
  const float* Wqkv = (const float*)d_in[1];
  const float* bqkv = (const float*)d_in[2];
  const float* Wout = (const float*)d_in[3];
  const float* bout = (const float*)d_in[4];
  float* y = (float*)d_out;

  char* ws = (char*)d_ws;
  unsigned short* Wvt  = (unsigned short*)(ws);             //   524,288 B  [128][2048] bf16
  unsigned short* Wst  = (unsigned short*)(ws + 524288);    //   524,288 B  [2048][128] bf16
  float*          beff = (float*)(ws + 1048576);            //     8,192 B
  unsigned short* T    = (unsigned short*)(ws + 1056768);   // 4,194,304 B  [16384][128] bf16

  k_prep<<<2048, 256, 0, stream>>>(Wqkv, Wout, Wvt, Wst);
  k_beff<<<8, 256, 0, stream>>>(bqkv, Wst, bout, beff);
  k_gemm1<<<512, 256, 0, stream>>>(x, Wvt, T);
  k_gemm2<<<dim3(256, 16), 256, 0, stream>>>(T, Wst, beff, y);
}